// Round 9
// baseline (243.594 us; speedup 1.0000x reference)
//
#include <hip/hip_runtime.h>

typedef unsigned short u16;
typedef unsigned int   u32;
using bf16x8 = __attribute__((ext_vector_type(8))) short;
using f32x4  = __attribute__((ext_vector_type(4))) float;
using u32x4  = __attribute__((ext_vector_type(4))) u32;

static constexpr int Bb = 8, Ll = 1024, Cc = 1024, Hh = 16, Dd = 64;
static constexpr int Mrows = Bb * Ll;   // 8192
static constexpr int N3    = 3 * Cc;    // 3072
// exp(S/8) = 2^(S * 0.125*log2(e)); fold into q at the QKV epilogue
static constexpr float QSCALE = 0.125f * 1.44269504088896f;

__device__ __forceinline__ u16 f2b(float f) {  // fp32 -> bf16 RNE
    u32 u = __builtin_bit_cast(u32, f);
    u += 0x7FFFu + ((u >> 16) & 1u);
    return (u16)(u >> 16);
}
__device__ __forceinline__ float b2f(u16 u) {
    return __builtin_bit_cast(float, (u32)u << 16);
}
__device__ __forceinline__ u32 pack2bf(float a, float b) {
    return (u32)f2b(a) | ((u32)f2b(b) << 16);
}
// async global->LDS, 16B/lane; LDS dest is wave-uniform base (lane*16 HW-added)
__device__ __forceinline__ void gload16(const u16* g, u16* l) {
    __builtin_amdgcn_global_load_lds(
        (const __attribute__((address_space(1))) void*)g,
        (__attribute__((address_space(3))) void*)l, 16, 0, 0);
}

// ---------------- fp32 -> bf16 convert, 16 elems/thread ----------------
__global__ void k_f32_to_bf16(const float* __restrict__ in, u16* __restrict__ out, int n16) {
    int idx = blockIdx.x * blockDim.x + threadIdx.x;
    if (idx >= n16) return;
    #pragma unroll
    for (int h = 0; h < 2; ++h) {
        f32x4 v0 = *((const f32x4*)in + idx * 4 + h * 2);
        f32x4 v1 = *((const f32x4*)in + idx * 4 + h * 2 + 1);
        u32x4 o;
        o[0] = pack2bf(v0[0], v0[1]);
        o[1] = pack2bf(v0[2], v0[3]);
        o[2] = pack2bf(v1[0], v1[1]);
        o[3] = pack2bf(v1[2], v1[3]);
        *((u32x4*)out + idx * 2 + h) = o;
    }
}

// ---- fused weight transpose+convert: W_qkv (1024x3072) and W_proj (1024x1024) ----
__global__ void k_transpose_w(const float* __restrict__ Wqkv, u16* __restrict__ WqkvT,
                              const float* __restrict__ Wproj, u16* __restrict__ WprojT) {
    __shared__ float tile[32][33];
    int bx = blockIdx.x;
    const float* in; u16* out; int Cn;
    if (bx < 96) { in = Wqkv;  out = WqkvT;  Cn = N3; }
    else         { in = Wproj; out = WprojT; Cn = Cc; bx -= 96; }
    const int R = Cc;   // 1024 rows for both
    int tx = threadIdx.x, ty = threadIdx.y;
    int c = bx * 32 + tx;
    int rbase = blockIdx.y * 32;
    #pragma unroll
    for (int rr = 0; rr < 4; ++rr)
        tile[ty + rr * 8][tx] = in[(size_t)(rbase + ty + rr * 8) * Cn + c];
    __syncthreads();
    int ro = bx * 32 + ty;
    #pragma unroll
    for (int rr = 0; rr < 4; ++rr)
        out[(size_t)(ro + rr * 8) * R + rbase + tx] = f2b(tile[tx][ty + rr * 8]);
}

// --- batched bf16 transpose: v (bh,L,D) -> vt (bh,D,L) ---
__global__ void k_transpose_bf16_batched(const u16* __restrict__ in, u16* __restrict__ out,
                                         int R, int Cn) {
    __shared__ u16 tile[32][33];
    size_t base = (size_t)blockIdx.z * R * Cn;
    int tx = threadIdx.x, ty = threadIdx.y;
    int c = blockIdx.x * 32 + tx;
    int rbase = blockIdx.y * 32;
    #pragma unroll
    for (int rr = 0; rr < 4; ++rr)
        tile[ty + rr * 8][tx] = in[base + (size_t)(rbase + ty + rr * 8) * Cn + c];
    __syncthreads();
    int ro = blockIdx.x * 32 + ty;
    #pragma unroll
    for (int rr = 0; rr < 4; ++rr)
        out[base + (size_t)(ro + rr * 8) * R + rbase + tx] = tile[tx][ty + rr * 8];
}

// ======== QKV GEMM: 8-phase 256x256 template (T3+T4+T2+T5, guide Sec 5) ========
// 512 thr = 8 waves (2M x 4N), per-wave out 128x64. BK=64, double-buffered
// 128KiB LDS, global_load_lds staging with both-sides XOR swizzle (rule 21):
// source chunk (tid&7)^(srow&7) -> linear LDS; reads XOR (ks*4+lg)^(lr&7).
// Counted vmcnt(8) at tile boundary only; raw s_barrier phases; setprio MFMA.
__global__ __launch_bounds__(512, 2)
void k_gemm_qkv8(const u16* __restrict__ A, const u16* __restrict__ Bt,
                 const float* __restrict__ bias,
                 u16* __restrict__ qo, u16* __restrict__ ko, u16* __restrict__ vo)
{
    const int K = Cc;            // 1024
    const int NT = K / 64;       // 16 K-tiles
    __shared__ u16 As[2][256 * 64];
    __shared__ u16 Bs[2][256 * 64];
    const int tid = threadIdx.x;
    const int wid = tid >> 6, lane = tid & 63;
    const int lr = lane & 15, lg = lane >> 4;
    const int wr = wid >> 2;          // 0..1 (M)
    const int wcn = wid & 3;          // 0..3 (N)
    const int nwg = gridDim.x * gridDim.y;       // 384, %8==0
    const int flat = blockIdx.y * gridDim.x + blockIdx.x;
    const int swz = (flat & 7) * (nwg >> 3) + (flat >> 3);
    const int bx = swz % gridDim.x, by = swz / gridDim.x;
    const int row0 = by * 256, col0 = bx * 256;

    const int srow = tid >> 3;                           // 0..63
    const int scol = ((tid & 7) ^ (srow & 7)) << 3;      // XOR-swizzled source chunk
    const u16* gA = A  + (size_t)(row0 + srow) * K + scol;
    const u16* gB = Bt + (size_t)(col0 + srow) * K + scol;
    u16* lA0 = &As[0][wid * 512]; u16* lB0 = &Bs[0][wid * 512];
    u16* lA1 = &As[1][wid * 512]; u16* lB1 = &Bs[1][wid * 512];

#define STG(lA, lB, t) do { \
    const u16* ga_ = gA + (size_t)(t) * 64; \
    const u16* gb_ = gB + (size_t)(t) * 64; \
    gload16(ga_,                  lA); \
    gload16(ga_ + (size_t)64 * K, lA + 4096); \
    gload16(ga_ + (size_t)128 * K, lA + 8192); \
    gload16(ga_ + (size_t)192 * K, lA + 12288); \
    gload16(gb_,                  lB); \
    gload16(gb_ + (size_t)64 * K, lB + 4096); \
    gload16(gb_ + (size_t)128 * K, lB + 8192); \
    gload16(gb_ + (size_t)192 * K, lB + 12288); \
} while (0)

    // per-lane swizzled k-chunk byte offsets (elem units): (ks*4+lg)^(lr&7)
    const int lx = lr & 7;
    const int coff0 = ((lg ^ lx) << 3);
    const int coff1 = (((4 + lg) ^ lx) << 3);

    f32x4 acc[8][4] = {};

    STG(lA0, lB0, 0);
    STG(lA1, lB1, 1);
    asm volatile("s_waitcnt vmcnt(8)" ::: "memory");   // tile0 landed (own 8 oldest)
    __builtin_amdgcn_s_barrier();                      // all waves' tile0 landed
    __builtin_amdgcn_sched_barrier(0);

    for (int t = 0; t < NT; ++t) {
        const u16* cA = (t & 1) ? &As[1][0] : &As[0][0];
        const u16* cB = (t & 1) ? &Bs[1][0] : &Bs[0][0];
        #pragma unroll
        for (int p = 0; p < 4; ++p) {
            const int mh = p >> 1, nh = p & 1;
            bf16x8 af[4][2], bfr[2][2];
            #pragma unroll
            for (int mf = 0; mf < 4; ++mf) {
                int rowL = wr * 128 + mh * 64 + mf * 16 + lr;
                af[mf][0] = *(const bf16x8*)&cA[rowL * 64 + coff0];
                af[mf][1] = *(const bf16x8*)&cA[rowL * 64 + coff1];
            }
            #pragma unroll
            for (int nf = 0; nf < 2; ++nf) {
                int rowL = wcn * 64 + nh * 32 + nf * 16 + lr;
                bfr[nf][0] = *(const bf16x8*)&cB[rowL * 64 + coff0];
                bfr[nf][1] = *(const bf16x8*)&cB[rowL * 64 + coff1];
            }
            __builtin_amdgcn_s_setprio(1);
            #pragma unroll
            for (int mf = 0; mf < 4; ++mf)
                #pragma unroll
                for (int nf = 0; nf < 2; ++nf) {
                    acc[mh*4+mf][nh*2+nf] = __builtin_amdgcn_mfma_f32_16x16x32_bf16(
                        af[mf][0], bfr[nf][0], acc[mh*4+mf][nh*2+nf], 0, 0, 0);
                    acc[mh*4+mf][nh*2+nf] = __builtin_amdgcn_mfma_f32_16x16x32_bf16(
                        af[mf][1], bfr[nf][1], acc[mh*4+mf][nh*2+nf], 0, 0, 0);
                }
            __builtin_amdgcn_s_setprio(0);
            if (p < 3) __builtin_amdgcn_s_barrier();
        }
        // tile boundary: protect buf before restage, then wait tile t+1
        asm volatile("" ::: "memory");
        __builtin_amdgcn_s_barrier();          // all waves done reading buf
        __builtin_amdgcn_sched_barrier(0);
        if (t + 2 < NT) {
            if (t & 1) STG(lA1, lB1, t + 2);
            else       STG(lA0, lB0, t + 2);
        }
        if (t + 1 < NT) {
            if (t + 2 < NT) { asm volatile("s_waitcnt vmcnt(8)" ::: "memory"); }
            else            { asm volatile("s_waitcnt vmcnt(0)" ::: "memory"); }
            __builtin_amdgcn_s_barrier();      // all waves' t+1 landed
            __builtin_amdgcn_sched_barrier(0);
        }
    }
#undef STG

    // epilogue: R6-proven q/k/v scatter to (B,H,L,D)
    #pragma unroll
    for (int m = 0; m < 8; ++m) {
        int rg0 = row0 + wr * 128 + m * 16 + lg * 4;
        #pragma unroll
        for (int n = 0; n < 4; ++n) {
            int cg = col0 + wcn * 64 + n * 16 + lr;
            float bv = bias[cg];
            int which = cg >> 10;         // 0=q 1=k 2=v
            float sc = (which == 0) ? QSCALE : 1.0f;
            int cc2 = cg & 1023;
            int h = cc2 >> 6, dd = cc2 & 63;
            #pragma unroll
            for (int r = 0; r < 4; ++r) {
                int rg = rg0 + r;
                int bidx = rg >> 10, ll2 = rg & 1023;
                size_t o = ((size_t)(bidx * Hh + h) * Ll + ll2) * Dd + dd;
                u16 val = f2b((acc[m][n][r] + bv) * sc);
                if (which == 0) qo[o] = val;
                else if (which == 1) ko[o] = val;
                else vo[o] = val;
            }
        }
    }
}

// ---- proj GEMM: 2-phase dbuf + global_load_lds + source-side XOR swizzle ----
__global__ __launch_bounds__(256)
void k_gemm_proj(const u16* __restrict__ A, const u16* __restrict__ Bt,
                 const float* __restrict__ bias, float* __restrict__ outf)
{
    const int N = Cc, K = Cc;
    __shared__ u16 As[2][128 * 32];
    __shared__ u16 Bs[2][128 * 32];
    const int tid = threadIdx.x;
    const int wid = tid >> 6, lane = tid & 63;
    const int lr = lane & 15, lg = lane >> 4;
    const int wr = wid >> 1, wc = wid & 1;
    const int nwg = gridDim.x * gridDim.y;
    const int flat = blockIdx.y * gridDim.x + blockIdx.x;
    const int swz = (flat & 7) * (nwg >> 3) + (flat >> 3);
    const int bx = swz % gridDim.x, by = swz / gridDim.x;
    const int row0 = by * 128, col0 = bx * 128;

    const int srow = wid * 32 + (lane >> 2);
    const int schk = (lane & 3) ^ (srow & 3);
    const u16* aP = A  + (size_t)(row0 + srow) * K + schk * 8;
    const u16* bP = Bt + (size_t)(col0 + srow) * K + schk * 8;
    const size_t r16 = (size_t)16 * K;
    u16* aL0 = &As[0][wid * 32 * 32]; u16* aL0b = aL0 + 16 * 32;
    u16* bL0 = &Bs[0][wid * 32 * 32]; u16* bL0b = bL0 + 16 * 32;
    u16* aL1 = &As[1][wid * 32 * 32]; u16* aL1b = aL1 + 16 * 32;
    u16* bL1 = &Bs[1][wid * 32 * 32]; u16* bL1b = bL1 + 16 * 32;

    f32x4 acc[4][4] = {};

#define STAGE0(kk) { gload16(aP + (kk), aL0); gload16(aP + r16 + (kk), aL0b); \
                     gload16(bP + (kk), bL0); gload16(bP + r16 + (kk), bL0b); }
#define STAGE1(kk) { gload16(aP + (kk), aL1); gload16(aP + r16 + (kk), aL1b); \
                     gload16(bP + (kk), bL1); gload16(bP + r16 + (kk), bL1b); }
#define COMPUTE(bufi) { \
        bf16x8 af[4], bfv[4]; \
        _Pragma("unroll") \
        for (int m = 0; m < 4; ++m) { int rw = wr * 64 + m * 16 + lr; \
            af[m] = *(const bf16x8*)&As[bufi][rw * 32 + ((lg ^ (rw & 3)) * 8)]; } \
        _Pragma("unroll") \
        for (int n = 0; n < 4; ++n) { int rw = wc * 64 + n * 16 + lr; \
            bfv[n] = *(const bf16x8*)&Bs[bufi][rw * 32 + ((lg ^ (rw & 3)) * 8)]; } \
        _Pragma("unroll") \
        for (int m = 0; m < 4; ++m) \
            _Pragma("unroll") \
            for (int n = 0; n < 4; ++n) \
                acc[m][n] = __builtin_amdgcn_mfma_f32_16x16x32_bf16(af[m], bfv[n], acc[m][n], 0, 0, 0); }

    STAGE0(0);
    __syncthreads();
    for (int k0 = 0; k0 < K; k0 += 64) {
        if (k0 + 32 < K) STAGE1(k0 + 32);
        COMPUTE(0);
        __syncthreads();
        if (k0 + 64 < K) STAGE0(k0 + 64);
        COMPUTE(1);
        __syncthreads();
    }
#undef STAGE0
#undef STAGE1
#undef COMPUTE

    #pragma unroll
    for (int m = 0; m < 4; ++m) {
        int rb2 = row0 + wr * 64 + m * 16 + lg * 4;
        #pragma unroll
        for (int n = 0; n < 4; ++n) {
            int cg = col0 + wc * 64 + n * 16 + lr;
            float bv = bias[cg];
            #pragma unroll
            for (int r = 0; r < 4; ++r)
                outf[(size_t)(rb2 + r) * N + cg] = acc[m][n][r] + bv;
        }
    }
}

// ---------------- attention pass 1: column sums ----------------
__global__ __launch_bounds__(256)
void k_attn_colsum(const u16* __restrict__ Q, const u16* __restrict__ Kb,
                   float* __restrict__ zinv)
{
    const int tid = threadIdx.x;
    const int wid = tid >> 6, lane = tid & 63;
    const int lr = lane & 15, lg = lane >> 4;
    const int fid = blockIdx.x;
    const int xcd = fid & 7, n = fid >> 3;
    const int pr = n & 3;
    const int bh = (xcd << 4) | (n >> 2);
    const u16* Qp = Q  + (size_t)bh * Ll * Dd;
    const u16* Kp = Kb + (size_t)bh * Ll * Dd;
    const bool dmask[4] = { lg * 4 + 0 >= lr, lg * 4 + 1 >= lr,
                            lg * 4 + 2 >= lr, lg * 4 + 3 >= lr };

    #pragma unroll
    for (int t = 0; t < 2; ++t) {
        const int xt = t ? (7 - pr) : pr;
        const int jw = xt * 128 + wid * 32;
        bf16x8 kb[2][2];
        #pragma unroll
        for (int g = 0; g < 2; ++g) {
            kb[g][0] = *(const bf16x8*)&Kp[(jw + g * 16 + lr) * Dd + lg * 8];
            kb[g][1] = *(const bf16x8*)&Kp[(jw + g * 16 + lr) * Dd + 32 + lg * 8];
        }
        float z0 = 0.f, z1 = 0.f;
        {   // ib = jw: g0 diag-masked; g1 entirely above diagonal (skip)
            bf16x8 qa0 = *(const bf16x8*)&Qp[(jw + lr) * Dd + lg * 8];
            bf16x8 qa1 = *(const bf16x8*)&Qp[(jw + lr) * Dd + 32 + lg * 8];
            f32x4 s = {0.f, 0.f, 0.f, 0.f};
            s = __builtin_amdgcn_mfma_f32_16x16x32_bf16(qa0, kb[0][0], s, 0, 0, 0);
            s = __builtin_amdgcn_mfma_f32_16x16x32_bf16(qa1, kb[0][1], s, 0, 0, 0);
            #pragma unroll
            for (int r = 0; r < 4; ++r) z0 += dmask[r] ? exp2f(s[r]) : 0.f;
        }
        {   // ib = jw+16: g0 unmasked, g1 diag-masked
            bf16x8 qa0 = *(const bf16x8*)&Qp[(jw + 16 + lr) * Dd + lg * 8];
            bf16x8 qa1 = *(const bf16x8*)&Qp[(jw + 16 + lr) * Dd + 32 + lg * 8];
            f32x4 s0 = {0.f, 0.f, 0.f, 0.f}, s1 = {0.f, 0.f, 0.f, 0.f};
            s0 = __builtin_amdgcn_mfma_f32_16x16x32_bf16(qa0, kb[0][0], s0, 0, 0, 0);
            s0 = __builtin_amdgcn_mfma_f32_16x16x32_bf16(qa1, kb[0][1], s0, 0, 0, 0);
            s1 = __builtin_amdgcn_mfma_f32_16x16x32_bf16(qa0, kb[1][0], s1, 0, 0, 0);
            s1 = __builtin_amdgcn_mfma_f32_16x16x32_bf16(qa1, kb[1][1], s1, 0, 0, 0);
            #pragma unroll
            for (int r = 0; r < 4; ++r) {
                z0 += exp2f(s0[r]);
                z1 += dmask[r] ? exp2f(s1[r]) : 0.f;
            }
        }
        for (int ib = jw + 32; ib < Ll; ib += 16) {
            bf16x8 qa0 = *(const bf16x8*)&Qp[(ib + lr) * Dd + lg * 8];
            bf16x8 qa1 = *(const bf16x8*)&Qp[(ib + lr) * Dd + 32 + lg * 8];
            f32x4 s0 = {0.f, 0.f, 0.f, 0.f}, s1 = {0.f, 0.f, 0.f, 0.f};
            s0 = __builtin_amdgcn_mfma_f32_16x16x32_bf16(qa0, kb[0][0], s0, 0, 0, 0);
            s0 = __builtin_amdgcn_mfma_f32_16x16x32_bf16(qa1, kb[0][1], s0, 0, 0, 0);
            s1 = __builtin_amdgcn_mfma_f32_16x16x32_bf16(qa0, kb[1][0], s1, 0, 0, 0);
            s1 = __builtin_amdgcn_mfma_f32_16x16x32_bf16(qa1, kb[1][1], s1, 0, 0, 0);
            #pragma unroll
            for (int r = 0; r < 4; ++r) { z0 += exp2f(s0[r]); z1 += exp2f(s1[r]); }
        }
        z0 += __shfl_xor(z0, 16); z0 += __shfl_xor(z0, 32);
        z1 += __shfl_xor(z1, 16); z1 += __shfl_xor(z1, 32);
        if (lg == 0) {
            zinv[(size_t)bh * Ll + jw + lr]      = 1.f / z0;
            zinv[(size_t)bh * Ll + jw + 16 + lr] = 1.f / z1;
        }
    }
}

// ---------------- attention pass 2: Y = (exp(S') * zinv_j) @ V^T ----------------
__global__ __launch_bounds__(256)
void k_attn_pv(const u16* __restrict__ Q, const u16* __restrict__ Kb,
               const u16* __restrict__ Vt, const float* __restrict__ zinv,
               u16* __restrict__ Y)
{
    __shared__ u16 Plds[4][32 * 72];
    const int tid = threadIdx.x;
    const int wid = tid >> 6, lane = tid & 63;
    const int lr = lane & 15, lg = lane >> 4;
    const int fid = blockIdx.x;
    const int xcd = fid & 7, n = fid >> 3;
    const int pr = n & 3;
    const int bh = (xcd << 4) | (n >> 2);
    const int bidx = bh >> 4, head = bh & 15;
    const u16* Qp = Q  + (size_t)bh * Ll * Dd;
    const u16* Kp = Kb + (size_t)bh * Ll * Dd;
    const u16* Vp = Vt + (size_t)bh * Ll * Dd;     // (Dd, Ll) layout
    const float* zp = zinv + (size_t)bh * Ll;
    u16* pl = &Plds[wid][0];

    #pragma unroll
    for (int t = 0; t < 2; ++t) {
        const int xt = t ? (7 - pr) : pr;
        const int iw = xt * 128 + wid * 32;
        bf16x8 qa[2][2];
        #pragma unroll
        for (int hh = 0; hh < 2; ++hh) {
            qa[hh][0] = *(const bf16x8*)&Qp[(iw + hh * 16 + lr) * Dd + lg * 8];
            qa[hh][1] = *(const bf16x8*)&Qp[(iw + hh * 16 + lr) * Dd + 32 + lg * 8];
        }
        f32x4 yacc[2][4] = {};

        for (int j0 = 0; j0 < iw + 32; j0 += 64) {
            #pragma unroll
            for (int cs = 0; cs < 4; ++cs) {
                int jb = j0 + cs * 16;
                bf16x8 kb0 = *(const bf16x8*)&Kp[(jb + lr) * Dd + lg * 8];
                bf16x8 kb1 = *(const bf16x8*)&Kp[(jb + lr) * Dd + 32 + lg * 8];
                f32x4 zv = *(const f32x4*)&zp[jb + 4 * lg];   // zinv[j], j=jb+4lg+r
                #pragma unroll
                for (int hh = 0; hh < 2; ++hh) {
                    f32x4 s = {0.f, 0.f, 0.f, 0.f};
                    s = __builtin_amdgcn_mfma_f32_16x16x32_bf16(kb0, qa[hh][0], s, 0, 0, 0);
                    s = __builtin_amdgcn_mfma_f32_16x16x32_bf16(kb1, qa[hh][1], s, 0, 0, 0);
                    float p[4];
                    if (jb + 15 <= iw + hh * 16) {
                        #pragma unroll
                        for (int r = 0; r < 4; ++r) p[r] = exp2f(s[r]) * zv[r];
                    } else {
                        int ig = iw + hh * 16 + lr;
                        #pragma unroll
                        for (int r = 0; r < 4; ++r)
                            p[r] = (jb + 4 * lg + r <= ig) ? exp2f(s[r]) * zv[r] : 0.f;
                    }
                    uint2 w;
                    w.x = pack2bf(p[0], p[1]);
                    w.y = pack2bf(p[2], p[3]);
                    *(uint2*)&pl[(hh * 16 + lr) * 72 + cs * 16 + 4 * lg] = w;
                }
            }
            asm volatile("s_waitcnt lgkmcnt(0)" ::: "memory");
            __builtin_amdgcn_sched_barrier(0);
            bf16x8 pa[2][2];
            #pragma unroll
            for (int hh = 0; hh < 2; ++hh) {
                pa[hh][0] = *(const bf16x8*)&pl[(hh * 16 + lr) * 72 + lg * 8];
                pa[hh][1] = *(const bf16x8*)&pl[(hh * 16 + lr) * 72 + 32 + lg * 8];
            }
            #pragma unroll
            for (int ns = 0; ns < 4; ++ns) {
                bf16x8 vb0 = *(const bf16x8*)&Vp[(size_t)(ns * 16 + lr) * Ll + j0 + lg * 8];
                bf16x8 vb1 = *(const bf16x8*)&Vp[(size_t)(ns * 16 + lr) * Ll + j0 + 32 + lg * 8];
                #pragma unroll
                for (int hh = 0; hh < 2; ++hh) {
                    yacc[hh][ns] = __builtin_amdgcn_mfma_f32_16x16x32_bf16(pa[hh][0], vb0, yacc[hh][ns], 0, 0, 0);
                    yacc[hh][ns] = __builtin_amdgcn_mfma_f32_16x16x32_bf16(pa[hh][1], vb1, yacc[hh][ns], 0, 0, 0);
                }
            }
        }
        #pragma unroll
        for (int hh = 0; hh < 2; ++hh)
            #pragma unroll
            for (int ns = 0; ns < 4; ++ns)
                #pragma unroll
                for (int r = 0; r < 4; ++r) {
                    int l2 = iw + hh * 16 + lg * 4 + r;
                    Y[((size_t)bidx * Ll + l2) * Cc + head * Dd + ns * 16 + lr] = f2b(yacc[hh][ns][r]);
                }
    }
}

extern "C" void kernel_launch(void* const* d_in, const int* in_sizes, int n_in,
                              void* d_out, int out_size, void* d_ws, size_t ws_size,
                              hipStream_t stream)
{
    const float* x     = (const float*)d_in[0];
    const float* Wqkv  = (const float*)d_in[1];
    const float* bqkv  = (const float*)d_in[2];
    const float* Wproj = (const float*)d_in[3];
    const float* bproj = (const float*)d_in[4];
    float* out = (float*)d_out;

    char* ws = (char*)d_ws;
    u16* xb     = (u16*)(ws + 0);            // x as bf16, 8192x1024         (16 MB)
    u16* WqkvT  = (u16*)(ws + 16777216);     // W_qkv^T bf16, 3072x1024      (6 MB)
    u16* WprojT = (u16*)(ws + 23068672);     // W_proj^T bf16, 1024x1024     (2 MB)
    u16* q      = (u16*)(ws + 25165824);     // (B,H,L,D) bf16, pre-scaled   (16 MB)
    u16* k      = (u16*)(ws + 41943040);     // (B,H,L,D) bf16               (16 MB)
    u16* v      = (u16*)(ws + 58720256);     // (B,H,L,D) bf16; reused as Y  (16 MB)
    u16* vt     = (u16*)(ws + 75497472);     // (B,H,D,L) bf16               (16 MB)
    float* zinv = (float*)(ws + 92274688);   // (B*H*L) fp32                 (0.5 MB)

    k_f32_to_bf16<<<dim3(2048), dim3(256), 0, stream>>>(x, xb, Mrows * Cc / 16);
    k_transpose_w<<<dim3(128, 32), dim3(32, 8), 0, stream>>>(Wqkv, WqkvT, Wproj, WprojT);
    k_gemm_qkv8<<<dim3(N3 / 256, Mrows / 256), dim3(512), 0, stream>>>(
        xb, WqkvT, bqkv, q, k, v);
    k_attn_colsum<<<dim3(512), dim3(256), 0, stream>>>(q, k, zinv);
    k_transpose_bf16_batched<<<dim3(2, 32, Bb * Hh), dim3(32, 8), 0, stream>>>(v, vt, Ll, Dd);
    k_attn_pv<<<dim3(512), dim3(256), 0, stream>>>(q, k, vt, zinv, v);
    k_gemm_proj<<<dim3(Cc / 128, Mrows / 128), dim3(256), 0, stream>>>(
        v, WprojT, bproj, out);
}

// Round 10
// 224.095 us; speedup vs baseline: 1.0870x; 1.0870x over previous
//
#include <hip/hip_runtime.h>

typedef unsigned short u16;
typedef unsigned int   u32;
using bf16x8 = __attribute__((ext_vector_type(8))) short;
using f32x4  = __attribute__((ext_vector_type(4))) float;
using f32x16 = __attribute__((ext_vector_type(16))) float;
using u32x4  = __attribute__((ext_vector_type(4))) u32;

static constexpr int Bb = 8, Ll = 1024, Cc = 1024, Hh = 16, Dd = 64;
static constexpr int Mrows = Bb * Ll;   // 8192
static constexpr int N3    = 3 * Cc;    // 3072
// exp(S/8) = 2^(S * 0.125*log2(e)); fold into q at the QKV epilogue
static constexpr float QSCALE = 0.125f * 1.44269504088896f;

__device__ __forceinline__ u16 f2b(float f) {  // fp32 -> bf16 RNE
    u32 u = __builtin_bit_cast(u32, f);
    u += 0x7FFFu + ((u >> 16) & 1u);
    return (u16)(u >> 16);
}
__device__ __forceinline__ float b2f(u16 u) {
    return __builtin_bit_cast(float, (u32)u << 16);
}
__device__ __forceinline__ u32 pack2bf(float a, float b) {
    return (u32)f2b(a) | ((u32)f2b(b) << 16);
}
// async global->LDS, 16B/lane; LDS dest is wave-uniform base (lane*16 HW-added)
__device__ __forceinline__ void gload16(const u16* g, u16* l) {
    __builtin_amdgcn_global_load_lds(
        (const __attribute__((address_space(1))) void*)g,
        (__attribute__((address_space(3))) void*)l, 16, 0, 0);
}

// ---------------- fp32 -> bf16 convert, 16 elems/thread ----------------
__global__ void k_f32_to_bf16(const float* __restrict__ in, u16* __restrict__ out, int n16) {
    int idx = blockIdx.x * blockDim.x + threadIdx.x;
    if (idx >= n16) return;
    #pragma unroll
    for (int h = 0; h < 2; ++h) {
        f32x4 v0 = *((const f32x4*)in + idx * 4 + h * 2);
        f32x4 v1 = *((const f32x4*)in + idx * 4 + h * 2 + 1);
        u32x4 o;
        o[0] = pack2bf(v0[0], v0[1]);
        o[1] = pack2bf(v0[2], v0[3]);
        o[2] = pack2bf(v1[0], v1[1]);
        o[3] = pack2bf(v1[2], v1[3]);
        *((u32x4*)out + idx * 2 + h) = o;
    }
}

// ---- fused weight transpose+convert: W_qkv (1024x3072) and W_proj (1024x1024) ----
__global__ void k_transpose_w(const float* __restrict__ Wqkv, u16* __restrict__ WqkvT,
                              const float* __restrict__ Wproj, u16* __restrict__ WprojT) {
    __shared__ float tile[32][33];
    int bx = blockIdx.x;
    const float* in; u16* out; int Cn;
    if (bx < 96) { in = Wqkv;  out = WqkvT;  Cn = N3; }
    else         { in = Wproj; out = WprojT; Cn = Cc; bx -= 96; }
    const int R = Cc;   // 1024 rows for both
    int tx = threadIdx.x, ty = threadIdx.y;
    int c = bx * 32 + tx;
    int rbase = blockIdx.y * 32;
    #pragma unroll
    for (int rr = 0; rr < 4; ++rr)
        tile[ty + rr * 8][tx] = in[(size_t)(rbase + ty + rr * 8) * Cn + c];
    __syncthreads();
    int ro = bx * 32 + ty;
    #pragma unroll
    for (int rr = 0; rr < 4; ++rr)
        out[(size_t)(ro + rr * 8) * R + rbase + tx] = f2b(tile[tx][ty + rr * 8]);
}

// --- batched bf16 transpose: v (bh,L,D) -> vt (bh,D,L) ---
__global__ void k_transpose_bf16_batched(const u16* __restrict__ in, u16* __restrict__ out,
                                         int R, int Cn) {
    __shared__ u16 tile[32][33];
    size_t base = (size_t)blockIdx.z * R * Cn;
    int tx = threadIdx.x, ty = threadIdx.y;
    int c = blockIdx.x * 32 + tx;
    int rbase = blockIdx.y * 32;
    #pragma unroll
    for (int rr = 0; rr < 4; ++rr)
        tile[ty + rr * 8][tx] = in[base + (size_t)(rbase + ty + rr * 8) * Cn + c];
    __syncthreads();
    int ro = blockIdx.x * 32 + ty;
    #pragma unroll
    for (int rr = 0; rr < 4; ++rr)
        out[base + (size_t)(ro + rr * 8) * R + rbase + tx] = tile[tx][ty + rr * 8];
}

// ======== QKV GEMM v3: 32x32x16 MFMA, 128^2 tile, BK=64, dbuf, 2 blocks/CU ========
// Rationale (R9 post-mortem): 16x16 fragments are LDS-BW-capped at 21 FLOP/LDS-byte;
// 32x32x16 doubles intensity to 32. 64KiB LDS -> 2 blocks/CU; grid 1536 = 3 exact
// rounds. Counted vmcnt(8) + both-sides XOR swizzle carried from R9 (verified: 0
// bank conflicts, correct). A/B frag: row|col=lane&31, k=8*(lane>>5)+e.
// C/D frag: col=lane&31, row=(reg&3)+8*(reg>>2)+4*(lane>>5).
__global__ __launch_bounds__(256, 2)
void k_gemm_qkv32(const u16* __restrict__ A, const u16* __restrict__ Bt,
                  const float* __restrict__ bias,
                  u16* __restrict__ qo, u16* __restrict__ ko, u16* __restrict__ vo)
{
    const int K = Cc;            // 1024
    const int NT = K / 64;       // 16 K-tiles
    __shared__ u16 As[2][128 * 64];
    __shared__ u16 Bs[2][128 * 64];
    const int tid = threadIdx.x;
    const int wid = tid >> 6, lane = tid & 63;
    const int l31 = lane & 31, lhi = lane >> 5, l7 = lane & 7;
    const int wr = wid >> 1, wc = wid & 1;       // 2x2 waves, 64x64 each
    const int nwg = gridDim.x * gridDim.y;       // 1536, %8==0
    const int flat = blockIdx.y * gridDim.x + blockIdx.x;
    const int swz = (flat & 7) * (nwg >> 3) + (flat >> 3);
    const int bx = swz % gridDim.x, by = swz / gridDim.x;
    const int row0 = by * 128, col0 = bx * 128;

    // staging: srow = tid>>3 (0..31; inst i adds 32), source chunk XOR-swizzled
    const int srow = tid >> 3;
    const int schunk = (tid & 7) ^ (srow & 7);
    const u16* gA = A  + (size_t)(row0 + srow) * K + schunk * 8;
    const u16* gB = Bt + (size_t)(col0 + srow) * K + schunk * 8;

#define STG(buf, t) do { \
    const u16* ga_ = gA + (size_t)(t) * 64; \
    const u16* gb_ = gB + (size_t)(t) * 64; \
    u16* la_ = &As[buf][wid * 512]; \
    u16* lb_ = &Bs[buf][wid * 512]; \
    gload16(ga_,                  la_); \
    gload16(ga_ + (size_t)32 * K, la_ + 2048); \
    gload16(ga_ + (size_t)64 * K, la_ + 4096); \
    gload16(ga_ + (size_t)96 * K, la_ + 6144); \
    gload16(gb_,                  lb_); \
    gload16(gb_ + (size_t)32 * K, lb_ + 2048); \
    gload16(gb_ + (size_t)64 * K, lb_ + 4096); \
    gload16(gb_ + (size_t)96 * K, lb_ + 6144); \
} while (0)

    // per-lane swizzled 16B-chunk offsets (elem units): chunk c = kc*2+lhi, c' = c^(row&7)
    const int coff0 = (((0 + lhi) ^ l7) << 3);
    const int coff1 = (((2 + lhi) ^ l7) << 3);
    const int coff2 = (((4 + lhi) ^ l7) << 3);
    const int coff3 = (((6 + lhi) ^ l7) << 3);
    const int coff[4] = { coff0, coff1, coff2, coff3 };

    f32x16 acc[2][2] = {};

    STG(0, 0);
    STG(1, 1);
    asm volatile("s_waitcnt vmcnt(8)" ::: "memory");   // tile0's 8 loads landed
    __builtin_amdgcn_s_barrier();
    __builtin_amdgcn_sched_barrier(0);

    for (int t = 0; t < NT; ++t) {
        const u16* cA = &As[t & 1][0];
        const u16* cB = &Bs[t & 1][0];
        // ---- phase 0: A frags (held) + B tn=0, 8 MFMA ----
        bf16x8 af[2][4], bf0[4];
        #pragma unroll
        for (int tm = 0; tm < 2; ++tm)
            #pragma unroll
            for (int kc = 0; kc < 4; ++kc)
                af[tm][kc] = *(const bf16x8*)&cA[(wr * 64 + tm * 32 + l31) * 64 + coff[kc]];
        #pragma unroll
        for (int kc = 0; kc < 4; ++kc)
            bf0[kc] = *(const bf16x8*)&cB[(wc * 64 + l31) * 64 + coff[kc]];
        __builtin_amdgcn_s_setprio(1);
        #pragma unroll
        for (int tm = 0; tm < 2; ++tm)
            #pragma unroll
            for (int kc = 0; kc < 4; ++kc)
                acc[tm][0] = __builtin_amdgcn_mfma_f32_32x32x16_bf16(
                    af[tm][kc], bf0[kc], acc[tm][0], 0, 0, 0);
        __builtin_amdgcn_s_setprio(0);
        __builtin_amdgcn_s_barrier();
        // ---- phase 1: B tn=1, 8 MFMA ----
        bf16x8 bf1[4];
        #pragma unroll
        for (int kc = 0; kc < 4; ++kc)
            bf1[kc] = *(const bf16x8*)&cB[(wc * 64 + 32 + l31) * 64 + coff[kc]];
        __builtin_amdgcn_s_setprio(1);
        #pragma unroll
        for (int tm = 0; tm < 2; ++tm)
            #pragma unroll
            for (int kc = 0; kc < 4; ++kc)
                acc[tm][1] = __builtin_amdgcn_mfma_f32_32x32x16_bf16(
                    af[tm][kc], bf1[kc], acc[tm][1], 0, 0, 0);
        __builtin_amdgcn_s_setprio(0);
        __builtin_amdgcn_s_barrier();          // all waves done reading buf[t&1]
        __builtin_amdgcn_sched_barrier(0);
        if (t + 2 < NT) STG(t & 1, t + 2);
        if (t + 1 < NT) {
            if (t + 2 < NT) { asm volatile("s_waitcnt vmcnt(8)" ::: "memory"); }
            else            { asm volatile("s_waitcnt vmcnt(0)" ::: "memory"); }
            __builtin_amdgcn_s_barrier();      // all waves' t+1 landed
            __builtin_amdgcn_sched_barrier(0);
        }
    }
#undef STG

    // epilogue: q/k/v scatter to (B,H,L,D); 32x32 C/D layout
    #pragma unroll
    for (int tm = 0; tm < 2; ++tm) {
        #pragma unroll
        for (int tn = 0; tn < 2; ++tn) {
            int cg = col0 + wc * 64 + tn * 32 + l31;
            float bv = bias[cg];
            int which = cg >> 10;         // 0=q 1=k 2=v
            float sc = (which == 0) ? QSCALE : 1.0f;
            int cc2 = cg & 1023;
            int h = cc2 >> 6, dd = cc2 & 63;
            int rbase = row0 + wr * 64 + tm * 32 + 4 * lhi;
            #pragma unroll
            for (int g = 0; g < 4; ++g) {
                #pragma unroll
                for (int r = 0; r < 4; ++r) {
                    int rg = rbase + 8 * g + r;
                    int bidx = rg >> 10, ll2 = rg & 1023;
                    size_t o = ((size_t)(bidx * Hh + h) * Ll + ll2) * Dd + dd;
                    u16 val = f2b((acc[tm][tn][g * 4 + r] + bv) * sc);
                    if (which == 0) qo[o] = val;
                    else if (which == 1) ko[o] = val;
                    else vo[o] = val;
                }
            }
        }
    }
}

// ---- proj GEMM: 2-phase dbuf + global_load_lds + source-side XOR swizzle ----
__global__ __launch_bounds__(256)
void k_gemm_proj(const u16* __restrict__ A, const u16* __restrict__ Bt,
                 const float* __restrict__ bias, float* __restrict__ outf)
{
    const int N = Cc, K = Cc;
    __shared__ u16 As[2][128 * 32];
    __shared__ u16 Bs[2][128 * 32];
    const int tid = threadIdx.x;
    const int wid = tid >> 6, lane = tid & 63;
    const int lr = lane & 15, lg = lane >> 4;
    const int wr = wid >> 1, wc = wid & 1;
    const int nwg = gridDim.x * gridDim.y;
    const int flat = blockIdx.y * gridDim.x + blockIdx.x;
    const int swz = (flat & 7) * (nwg >> 3) + (flat >> 3);
    const int bx = swz % gridDim.x, by = swz / gridDim.x;
    const int row0 = by * 128, col0 = bx * 128;

    const int srow = wid * 32 + (lane >> 2);
    const int schk = (lane & 3) ^ (srow & 3);
    const u16* aP = A  + (size_t)(row0 + srow) * K + schk * 8;
    const u16* bP = Bt + (size_t)(col0 + srow) * K + schk * 8;
    const size_t r16 = (size_t)16 * K;
    u16* aL0 = &As[0][wid * 32 * 32]; u16* aL0b = aL0 + 16 * 32;
    u16* bL0 = &Bs[0][wid * 32 * 32]; u16* bL0b = bL0 + 16 * 32;
    u16* aL1 = &As[1][wid * 32 * 32]; u16* aL1b = aL1 + 16 * 32;
    u16* bL1 = &Bs[1][wid * 32 * 32]; u16* bL1b = bL1 + 16 * 32;

    f32x4 acc[4][4] = {};

#define STAGE0(kk) { gload16(aP + (kk), aL0); gload16(aP + r16 + (kk), aL0b); \
                     gload16(bP + (kk), bL0); gload16(bP + r16 + (kk), bL0b); }
#define STAGE1(kk) { gload16(aP + (kk), aL1); gload16(aP + r16 + (kk), aL1b); \
                     gload16(bP + (kk), bL1); gload16(bP + r16 + (kk), bL1b); }
#define COMPUTE(bufi) { \
        bf16x8 af[4], bfv[4]; \
        _Pragma("unroll") \
        for (int m = 0; m < 4; ++m) { int rw = wr * 64 + m * 16 + lr; \
            af[m] = *(const bf16x8*)&As[bufi][rw * 32 + ((lg ^ (rw & 3)) * 8)]; } \
        _Pragma("unroll") \
        for (int n = 0; n < 4; ++n) { int rw = wc * 64 + n * 16 + lr; \
            bfv[n] = *(const bf16x8*)&Bs[bufi][rw * 32 + ((lg ^ (rw & 3)) * 8)]; } \
        _Pragma("unroll") \
        for (int m = 0; m < 4; ++m) \
            _Pragma("unroll") \
            for (int n = 0; n < 4; ++n) \
                acc[m][n] = __builtin_amdgcn_mfma_f32_16x16x32_bf16(af[m], bfv[n], acc[m][n], 0, 0, 0); }

    STAGE0(0);
    __syncthreads();
    for (int k0 = 0; k0 < K; k0 += 64) {
        if (k0 + 32 < K) STAGE1(k0 + 32);
        COMPUTE(0);
        __syncthreads();
        if (k0 + 64 < K) STAGE0(k0 + 64);
        COMPUTE(1);
        __syncthreads();
    }
#undef STAGE0
#undef STAGE1
#undef COMPUTE

    #pragma unroll
    for (int m = 0; m < 4; ++m) {
        int rb2 = row0 + wr * 64 + m * 16 + lg * 4;
        #pragma unroll
        for (int n = 0; n < 4; ++n) {
            int cg = col0 + wc * 64 + n * 16 + lr;
            float bv = bias[cg];
            #pragma unroll
            for (int r = 0; r < 4; ++r)
                outf[(size_t)(rb2 + r) * N + cg] = acc[m][n][r] + bv;
        }
    }
}

// ---------------- attention pass 1: column sums ----------------
__global__ __launch_bounds__(256)
void k_attn_colsum(const u16* __restrict__ Q, const u16* __restrict__ Kb,
                   float* __restrict__ zinv)
{
    const int tid = threadIdx.x;
    const int wid = tid >> 6, lane = tid & 63;
    const int lr = lane & 15, lg = lane >> 4;
    const int fid = blockIdx.x;
    const int xcd = fid & 7, n = fid >> 3;
    const int pr = n & 3;
    const int bh = (xcd << 4) | (n >> 2);
    const u16* Qp = Q  + (size_t)bh * Ll * Dd;
    const u16* Kp = Kb + (size_t)bh * Ll * Dd;
    const bool dmask[4] = { lg * 4 + 0 >= lr, lg * 4 + 1 >= lr,
                            lg * 4 + 2 >= lr, lg * 4 + 3 >= lr };

    #pragma unroll
    for (int t = 0; t < 2; ++t) {
        const int xt = t ? (7 - pr) : pr;
        const int jw = xt * 128 + wid * 32;
        bf16x8 kb[2][2];
        #pragma unroll
        for (int g = 0; g < 2; ++g) {
            kb[g][0] = *(const bf16x8*)&Kp[(jw + g * 16 + lr) * Dd + lg * 8];
            kb[g][1] = *(const bf16x8*)&Kp[(jw + g * 16 + lr) * Dd + 32 + lg * 8];
        }
        float z0 = 0.f, z1 = 0.f;
        {   // ib = jw: g0 diag-masked; g1 entirely above diagonal (skip)
            bf16x8 qa0 = *(const bf16x8*)&Qp[(jw + lr) * Dd + lg * 8];
            bf16x8 qa1 = *(const bf16x8*)&Qp[(jw + lr) * Dd + 32 + lg * 8];
            f32x4 s = {0.f, 0.f, 0.f, 0.f};
            s = __builtin_amdgcn_mfma_f32_16x16x32_bf16(qa0, kb[0][0], s, 0, 0, 0);
            s = __builtin_amdgcn_mfma_f32_16x16x32_bf16(qa1, kb[0][1], s, 0, 0, 0);
            #pragma unroll
            for (int r = 0; r < 4; ++r) z0 += dmask[r] ? exp2f(s[r]) : 0.f;
        }
        {   // ib = jw+16: g0 unmasked, g1 diag-masked
            bf16x8 qa0 = *(const bf16x8*)&Qp[(jw + 16 + lr) * Dd + lg * 8];
            bf16x8 qa1 = *(const bf16x8*)&Qp[(jw + 16 + lr) * Dd + 32 + lg * 8];
            f32x4 s0 = {0.f, 0.f, 0.f, 0.f}, s1 = {0.f, 0.f, 0.f, 0.f};
            s0 = __builtin_amdgcn_mfma_f32_16x16x32_bf16(qa0, kb[0][0], s0, 0, 0, 0);
            s0 = __builtin_amdgcn_mfma_f32_16x16x32_bf16(qa1, kb[0][1], s0, 0, 0, 0);
            s1 = __builtin_amdgcn_mfma_f32_16x16x32_bf16(qa0, kb[1][0], s1, 0, 0, 0);
            s1 = __builtin_amdgcn_mfma_f32_16x16x32_bf16(qa1, kb[1][1], s1, 0, 0, 0);
            #pragma unroll
            for (int r = 0; r < 4; ++r) {
                z0 += exp2f(s0[r]);
                z1 += dmask[r] ? exp2f(s1[r]) : 0.f;
            }
        }
        for (int ib = jw + 32; ib < Ll; ib += 16) {
            bf16x8 qa0 = *(const bf16x8*)&Qp[(ib + lr) * Dd + lg * 8];
            bf16x8 qa1 = *(const bf16x8*)&Qp[(ib + lr) * Dd + 32 + lg * 8];
            f32x4 s0 = {0.f, 0.f, 0.f, 0.f}, s1 = {0.f, 0.f, 0.f, 0.f};
            s0 = __builtin_amdgcn_mfma_f32_16x16x32_bf16(qa0, kb[0][0], s0, 0, 0, 0);
            s0 = __builtin_amdgcn_mfma_f32_16x16x32_bf16(qa1, kb[0][1], s0, 0, 0, 0);
            s1 = __builtin_amdgcn_mfma_f32_16x16x32_bf16(qa0, kb[1][0], s1, 0, 0, 0);
            s1 = __builtin_amdgcn_mfma_f32_16x16x32_bf16(qa1, kb[1][1], s1, 0, 0, 0);
            #pragma unroll
            for (int r = 0; r < 4; ++r) { z0 += exp2f(s0[r]); z1 += exp2f(s1[r]); }
        }
        z0 += __shfl_xor(z0, 16); z0 += __shfl_xor(z0, 32);
        z1 += __shfl_xor(z1, 16); z1 += __shfl_xor(z1, 32);
        if (lg == 0) {
            zinv[(size_t)bh * Ll + jw + lr]      = 1.f / z0;
            zinv[(size_t)bh * Ll + jw + 16 + lr] = 1.f / z1;
        }
    }
}

// ---------------- attention pass 2: Y = (exp(S') * zinv_j) @ V^T ----------------
__global__ __launch_bounds__(256)
void k_attn_pv(const u16* __restrict__ Q, const u16* __restrict__ Kb,
               const u16* __restrict__ Vt, const float* __restrict__ zinv,
               u16* __restrict__ Y)
{
    __shared__ u16 Plds[4][32 * 72];
    const int tid = threadIdx.x;
    const int wid = tid >> 6, lane = tid & 63;
    const int lr = lane & 15, lg = lane >> 4;
    const int fid = blockIdx.x;
    const int xcd = fid & 7, n = fid >> 3;
    const int pr = n & 3;
    const int bh = (xcd << 4) | (n >> 2);
    const int bidx = bh >> 4, head = bh & 15;
    const u16* Qp = Q  + (size_t)bh * Ll * Dd;
    const u16* Kp = Kb + (size_t)bh * Ll * Dd;
    const u16* Vp = Vt + (size_t)bh * Ll * Dd;     // (Dd, Ll) layout
    const float* zp = zinv + (size_t)bh * Ll;
    u16* pl = &Plds[wid][0];

    #pragma unroll
    for (int t = 0; t < 2; ++t) {
        const int xt = t ? (7 - pr) : pr;
        const int iw = xt * 128 + wid * 32;
        bf16x8 qa[2][2];
        #pragma unroll
        for (int hh = 0; hh < 2; ++hh) {
            qa[hh][0] = *(const bf16x8*)&Qp[(iw + hh * 16 + lr) * Dd + lg * 8];
            qa[hh][1] = *(const bf16x8*)&Qp[(iw + hh * 16 + lr) * Dd + 32 + lg * 8];
        }
        f32x4 yacc[2][4] = {};

        for (int j0 = 0; j0 < iw + 32; j0 += 64) {
            #pragma unroll
            for (int cs = 0; cs < 4; ++cs) {
                int jb = j0 + cs * 16;
                bf16x8 kb0 = *(const bf16x8*)&Kp[(jb + lr) * Dd + lg * 8];
                bf16x8 kb1 = *(const bf16x8*)&Kp[(jb + lr) * Dd + 32 + lg * 8];
                f32x4 zv = *(const f32x4*)&zp[jb + 4 * lg];   // zinv[j], j=jb+4lg+r
                #pragma unroll
                for (int hh = 0; hh < 2; ++hh) {
                    f32x4 s = {0.f, 0.f, 0.f, 0.f};
                    s = __builtin_amdgcn_mfma_f32_16x16x32_bf16(kb0, qa[hh][0], s, 0, 0, 0);
                    s = __builtin_amdgcn_mfma_f32_16x16x32_bf16(kb1, qa[hh][1], s, 0, 0, 0);
                    float p[4];
                    if (jb + 15 <= iw + hh * 16) {
                        #pragma unroll
                        for (int r = 0; r < 4; ++r) p[r] = exp2f(s[r]) * zv[r];
                    } else {
                        int ig = iw + hh * 16 + lr;
                        #pragma unroll
                        for (int r = 0; r < 4; ++r)
                            p[r] = (jb + 4 * lg + r <= ig) ? exp2f(s[r]) * zv[r] : 0.f;
                    }
                    uint2 w;
                    w.x = pack2bf(p[0], p[1]);
                    w.y = pack2bf(p[2], p[3]);
                    *(uint2*)&pl[(hh * 16 + lr) * 72 + cs * 16 + 4 * lg] = w;
                }
            }
            asm volatile("s_waitcnt lgkmcnt(0)" ::: "memory");
            __builtin_amdgcn_sched_barrier(0);
            bf16x8 pa[2][2];
            #pragma unroll
            for (int hh = 0; hh < 2; ++hh) {
                pa[hh][0] = *(const bf16x8*)&pl[(hh * 16 + lr) * 72 + lg * 8];
                pa[hh][1] = *(const bf16x8*)&pl[(hh * 16 + lr) * 72 + 32 + lg * 8];
            }
            #pragma unroll
            for (int ns = 0; ns < 4; ++ns) {
                bf16x8 vb0 = *(const bf16x8*)&Vp[(size_t)(ns * 16 + lr) * Ll + j0 + lg * 8];
                bf16x8 vb1 = *(const bf16x8*)&Vp[(size_t)(ns * 16 + lr) * Ll + j0 + 32 + lg * 8];
                #pragma unroll
                for (int hh = 0; hh < 2; ++hh) {
                    yacc[hh][ns] = __builtin_amdgcn_mfma_f32_16x16x32_bf16(pa[hh][0], vb0, yacc[hh][ns], 0, 0, 0);
                    yacc[hh][ns] = __builtin_amdgcn_mfma_f32_16x16x32_bf16(pa[hh][1], vb1, yacc[hh][ns], 0, 0, 0);
                }
            }
        }
        #pragma unroll
        for (int hh = 0; hh < 2; ++hh)
            #pragma unroll
            for (int ns = 0; ns < 4; ++ns)
                #pragma unroll
                for (int r = 0; r < 4; ++r) {
                    int l2 = iw + hh * 16 + lg * 4 + r;
                    Y[((size_t)bidx * Ll + l2) * Cc + head * Dd + ns * 16 + lr] = f2b(yacc[hh][ns][r]);
                }
    }
}

extern "C" void kernel_launch(void* const* d_in, const int* in_sizes, int n_in,
                              void* d_out, int out_size, void* d_ws, size_t ws_size,
                              hipStream_t stream)
{
    const float* x     = (const float*)d_in[0];
    const float* Wqkv  = (const float*)d_in[1];
    const float* bqkv  = (const float*)d_in[2];
    const float* Wproj = (const float*)d_in[3];
    const float* bproj = (const float*)d_in[4];
    float* out = (float*)d_out;

    char* ws = (char*)d_ws;
    u16* xb     = (u16*)(ws + 0);            // x as bf16, 8192x1024         (16 MB)
    u16* WqkvT  = (u16*)(ws + 16777216);     // W_qkv^T bf16, 3072x1024      (6 MB)
    u16* WprojT = (u16*)(ws + 23068672);     // W_proj^T bf16, 1024x1024     (2 MB)
    u16* q      = (u16*)(ws + 25165824);     // (B,H,L,D) bf16, pre-scaled   (16 MB)
    u16* k      = (u16*)(ws + 41943040);     // (B,H,L,D) bf16               (16 MB)
    u16* v      = (u16*)(ws + 58720256);     // (B,H,L,D) bf16; reused as Y  (16 MB)
    u16* vt     = (u16*)(ws + 75497472);     // (B,H,D,L) bf16               (16 MB)
    float* zinv = (float*)(ws + 92274688);   // (B*H*L) fp32                 (0.5 MB)

    k_f32_to_bf16<<<dim3(2048), dim3(256), 0, stream>>>(x, xb, Mrows * Cc / 16);
    k_transpose_w<<<dim3(128, 32), dim3(32, 8), 0, stream>>>(Wqkv, WqkvT, Wproj, WprojT);
    k_gemm_qkv32<<<dim3(N3 / 128, Mrows / 128), dim3(256), 0, stream>>>(
        xb, WqkvT, bqkv, q, k, v);
    k_attn_colsum<<<dim3(512), dim3(256), 0, stream>>>(q, k, zinv);
    k_transpose_bf16_batched<<<dim3(2, 32, Bb * Hh), dim3(32, 8), 0, stream>>>(v, vt, Ll, Dd);
    k_attn_pv<<<dim3(512), dim3(256), 0, stream>>>(q, k, vt, zinv, v);
    k_gemm_proj<<<dim3(Cc / 128, Mrows / 128), dim3(256), 0, stream>>>(
        v, WprojT, bproj, out);
}